// Round 14
// baseline (146.016 us; speedup 1.0000x reference)
//
#include <hip/hip_runtime.h>
#include <math.h>

#define B 8
#define T 128
#define I_TOK 196
#define TEXT_DIM 768
#define IMAGE_DIM 1024
#define HIDDEN 512
#define EXP_SCALE 2.88539008177792681f   // 2*log2(e): exp(2x) = 2^(EXP_SCALE*x)

#if __has_builtin(__builtin_amdgcn_exp2f)
#define FAST_EXP2(x) __builtin_amdgcn_exp2f(x)
#else
#define FAST_EXP2(x) exp2f(x)
#endif
#if __has_builtin(__builtin_amdgcn_rcpf)
#define FAST_RCP(x) __builtin_amdgcn_rcpf(x)
#else
#define FAST_RCP(x) __fdividef(1.f, (x))
#endif
#if __has_builtin(__builtin_amdgcn_sched_barrier)
#define SCHED_FENCE() __builtin_amdgcn_sched_barrier(0)
#else
#define SCHED_FENCE()
#endif

typedef short bf16x8 __attribute__((ext_vector_type(8)));
typedef float f32x4 __attribute__((ext_vector_type(4)));

// ---- fragment-tiled layout geometry (R9, unchanged) -----------------------
#define KT_T (TEXT_DIM / 32)
#define KT_I (IMAGE_DIM / 32)
#define MT_T (B * T / 16)
#define MT_I (B * I_TOK / 16)
#define NT   (HIDDEN / 16)

#define XT_ELEMS (MT_T * KT_T * 512)
#define XI_ELEMS (MT_I * KT_I * 512)
#define X_ELEMS  (XT_ELEMS + XI_ELEMS)
#define WT_T_ELEMS (NT * KT_T * 512)
#define W_ELEMS (WT_T_ELEMS + NT * KT_I * 512)

#define XTILES_T (MT_T * KT_T)
#define XTILES   (XTILES_T + MT_I * KT_I)
#define WTILES_T (NT * KT_T)
#define WTILES   (WTILES_T + NT * KT_I)
#define PREP_GRID ((XTILES + WTILES) / 4)

__device__ __forceinline__ unsigned short f2bf(float x) {
    unsigned int u = __float_as_uint(x);
    unsigned int r = u + 0x7FFFu + ((u >> 16) & 1u);   // RNE
    return (unsigned short)(r >> 16);
}
__device__ __forceinline__ float bf2f(unsigned short h) {
    return __uint_as_float(((unsigned int)h) << 16);
}

// ---------------- prep v9 (R9 exact — best measured) -----------------------
__global__ __launch_bounds__(256) void prep_kernel(
        const float* __restrict__ text, const float* __restrict__ image,
        const float* __restrict__ Wt, const float* __restrict__ Wi,
        unsigned short* __restrict__ Xh, unsigned short* __restrict__ Xl,
        unsigned short* __restrict__ WTh, unsigned short* __restrict__ WTl)
{
    const int tid = threadIdx.x;
    const int lane = tid & 63, wv = tid >> 6;
    const int r16 = lane & 15, quad = lane >> 4;
    const int id = blockIdx.x * 4 + wv;

    float v[8];
    unsigned short* oh;
    unsigned short* ol;
    long dst;

    if (id < XTILES) {
        const float* X; int K, mt, kt;
        if (id < XTILES_T) { X = text; K = TEXT_DIM; mt = id / KT_T; kt = id % KT_T; }
        else { const int i2 = id - XTILES_T; X = image; K = IMAGE_DIM; mt = i2 / KT_I; kt = i2 % KT_I; }
        const float* src = X + (long)(mt * 16 + r16) * K + kt * 32 + quad * 8;
        const float4 a = *(const float4*)src;
        const float4 b = *(const float4*)(src + 4);
        v[0]=a.x; v[1]=a.y; v[2]=a.z; v[3]=a.w; v[4]=b.x; v[5]=b.y; v[6]=b.z; v[7]=b.w;
        oh = (id < XTILES_T) ? Xh : Xh + XT_ELEMS;
        ol = (id < XTILES_T) ? Xl : Xl + XT_ELEMS;
        const long tile = (id < XTILES_T) ? id : (long)(id - XTILES_T);
        dst = tile * 512 + lane * 8;
    } else {
        const int idw = id - XTILES;
        const float* W; int K, nt, kt;
        if (idw < WTILES_T) { W = Wt; K = TEXT_DIM; nt = idw / KT_T; kt = idw % KT_T; }
        else { const int i2 = idw - WTILES_T; W = Wi; K = IMAGE_DIM; nt = i2 / KT_I; kt = i2 % KT_I; }
        const float* src = W + (long)(kt * 32 + quad * 8) * HIDDEN + nt * 16 + r16;
        #pragma unroll
        for (int j = 0; j < 8; ++j) v[j] = src[(long)j * HIDDEN];
        oh = (idw < WTILES_T) ? WTh : WTh + WT_T_ELEMS;
        ol = (idw < WTILES_T) ? WTl : WTl + WT_T_ELEMS;
        const long tile = (idw < WTILES_T) ? idw : (long)(idw - WTILES_T);
        dst = tile * 512 + lane * 8;
    }

    uint4 hv, lv;
    unsigned int hh[8], ll[8];
    #pragma unroll
    for (int j = 0; j < 8; ++j) {
        hh[j] = f2bf(v[j]);
        ll[j] = f2bf(v[j] - bf2f((unsigned short)hh[j]));
    }
    hv.x = hh[0] | (hh[1] << 16); hv.y = hh[2] | (hh[3] << 16);
    hv.z = hh[4] | (hh[5] << 16); hv.w = hh[6] | (hh[7] << 16);
    lv.x = ll[0] | (ll[1] << 16); lv.y = ll[2] | (ll[3] << 16);
    lv.z = ll[4] | (ll[5] << 16); lv.w = ll[6] | (ll[7] << 16);
    *(uint4*)(oh + dst) = hv;
    *(uint4*)(ol + dst) = lv;
}

// ---------------- MFMA projections v9 (R9 exact) ---------------------------
#define GT_BLOCKS (32 * 8)
#define GI_BLOCKS (49 * 8)
#define GEMM_GRID (GT_BLOCKS + GI_BLOCKS)
#define PSTRIDE 66

__global__ __launch_bounds__(256, 2) void mfma_proj_kernel(
        const unsigned short* __restrict__ Xh, const unsigned short* __restrict__ Xl,
        const unsigned short* __restrict__ WTh, const unsigned short* __restrict__ WTl,
        const float* __restrict__ bt, const float* __restrict__ bi,
        float* __restrict__ pt, float* __restrict__ pi)
{
    __shared__ float part[32 * PSTRIDE];

    const int tid = threadIdx.x;
    const int lane = tid & 63, wv = tid >> 6;
    const int r16 = lane & 15, quad = lane >> 4;
    const int nh = wv & 1;
    const int kh = wv >> 1;

    int bid = blockIdx.x;
    const unsigned short *xh, *xl, *wh, *wl; const float* bias; float* Y;
    int ktiles;
    if (bid < GT_BLOCKS) {
        xh = Xh; xl = Xl; wh = WTh; wl = WTl; bias = bt; Y = pt; ktiles = KT_T;
    } else {
        bid -= GT_BLOCKS;
        xh = Xh + XT_ELEMS; xl = Xl + XT_ELEMS;
        wh = WTh + WT_T_ELEMS; wl = WTl + WT_T_ELEMS;
        bias = bi; Y = pi; ktiles = KT_I;
    }
    const int m0 = (bid >> 3) * 32;
    const int n0 = (bid & 7) * 64 + nh * 32;
    const int nstep = ktiles >> 1;
    const int kt0 = kh * nstep;
    const int mt0 = (bid >> 3) * 2;
    const int nt0 = (bid & 7) * 4 + nh * 2;

    const unsigned short* pa0 = xh + ((long)mt0 * ktiles + kt0) * 512 + lane * 8;
    const unsigned short* pa1 = pa0 + (long)ktiles * 512;
    const unsigned short* qa0 = xl + ((long)mt0 * ktiles + kt0) * 512 + lane * 8;
    const unsigned short* qa1 = qa0 + (long)ktiles * 512;
    const unsigned short* pb0 = wh + ((long)nt0 * ktiles + kt0) * 512 + lane * 8;
    const unsigned short* pb1 = pb0 + (long)ktiles * 512;
    const unsigned short* qb0 = wl + ((long)nt0 * ktiles + kt0) * 512 + lane * 8;
    const unsigned short* qb1 = qb0 + (long)ktiles * 512;

    f32x4 a00 = {0,0,0,0}, a01 = {0,0,0,0}, a10 = {0,0,0,0}, a11 = {0,0,0,0};

    bf16x8 Ah0 = *(const bf16x8*)(pa0);
    bf16x8 Ah1 = *(const bf16x8*)(pa1);
    bf16x8 Al0 = *(const bf16x8*)(qa0);
    bf16x8 Al1 = *(const bf16x8*)(qa1);
    bf16x8 Bh0 = *(const bf16x8*)(pb0);
    bf16x8 Bh1 = *(const bf16x8*)(pb1);
    bf16x8 Bl0 = *(const bf16x8*)(qb0);
    bf16x8 Bl1 = *(const bf16x8*)(qb1);

    for (int s = 0; s < nstep; ++s) {
        const long kn = (s + 1 < nstep) ? (long)(s + 1) * 512 : 0;
        const bf16x8 nAh0 = *(const bf16x8*)(pa0 + kn);
        const bf16x8 nAh1 = *(const bf16x8*)(pa1 + kn);
        const bf16x8 nAl0 = *(const bf16x8*)(qa0 + kn);
        const bf16x8 nAl1 = *(const bf16x8*)(qa1 + kn);
        const bf16x8 nBh0 = *(const bf16x8*)(pb0 + kn);
        const bf16x8 nBh1 = *(const bf16x8*)(pb1 + kn);
        const bf16x8 nBl0 = *(const bf16x8*)(qb0 + kn);
        const bf16x8 nBl1 = *(const bf16x8*)(qb1 + kn);
        SCHED_FENCE();

        a00 = __builtin_amdgcn_mfma_f32_16x16x32_bf16(Ah0, Bh0, a00, 0, 0, 0);
        a01 = __builtin_amdgcn_mfma_f32_16x16x32_bf16(Ah0, Bh1, a01, 0, 0, 0);
        a10 = __builtin_amdgcn_mfma_f32_16x16x32_bf16(Ah1, Bh0, a10, 0, 0, 0);
        a11 = __builtin_amdgcn_mfma_f32_16x16x32_bf16(Ah1, Bh1, a11, 0, 0, 0);
        a00 = __builtin_amdgcn_mfma_f32_16x16x32_bf16(Ah0, Bl0, a00, 0, 0, 0);
        a01 = __builtin_amdgcn_mfma_f32_16x16x32_bf16(Ah0, Bl1, a01, 0, 0, 0);
        a10 = __builtin_amdgcn_mfma_f32_16x16x32_bf16(Ah1, Bl0, a10, 0, 0, 0);
        a11 = __builtin_amdgcn_mfma_f32_16x16x32_bf16(Ah1, Bl1, a11, 0, 0, 0);
        a00 = __builtin_amdgcn_mfma_f32_16x16x32_bf16(Al0, Bh0, a00, 0, 0, 0);
        a01 = __builtin_amdgcn_mfma_f32_16x16x32_bf16(Al0, Bh1, a01, 0, 0, 0);
        a10 = __builtin_amdgcn_mfma_f32_16x16x32_bf16(Al1, Bh0, a10, 0, 0, 0);
        a11 = __builtin_amdgcn_mfma_f32_16x16x32_bf16(Al1, Bh1, a11, 0, 0, 0);
        SCHED_FENCE();

        Ah0 = nAh0; Ah1 = nAh1; Al0 = nAl0; Al1 = nAl1;
        Bh0 = nBh0; Bh1 = nBh1; Bl0 = nBl0; Bl1 = nBl1;
    }

    const int lc = nh * 32 + r16;
    if (kh == 1) {
        #pragma unroll
        for (int r = 0; r < 4; ++r) {
            part[(quad * 4 + r) * PSTRIDE + lc]           = a00[r];
            part[(quad * 4 + r) * PSTRIDE + lc + 16]      = a01[r];
            part[(quad * 4 + 16 + r) * PSTRIDE + lc]      = a10[r];
            part[(quad * 4 + 16 + r) * PSTRIDE + lc + 16] = a11[r];
        }
    }
    __syncthreads();
    if (kh == 0) {
        const int row0 = m0 + quad * 4;
        const float bv0 = bias[n0 + r16];
        const float bv1 = bias[n0 + 16 + r16];
        #pragma unroll
        for (int r = 0; r < 4; ++r) {
            const float v00 = (a00[r] + part[(quad * 4 + r) * PSTRIDE + lc]           + bv0) * EXP_SCALE;
            const float v01 = (a01[r] + part[(quad * 4 + r) * PSTRIDE + lc + 16]      + bv1) * EXP_SCALE;
            const float v10 = (a10[r] + part[(quad * 4 + 16 + r) * PSTRIDE + lc]      + bv0) * EXP_SCALE;
            const float v11 = (a11[r] + part[(quad * 4 + 16 + r) * PSTRIDE + lc + 16] + bv1) * EXP_SCALE;
            Y[(long)(row0 + r)      * HIDDEN + n0 + r16]      = FAST_EXP2(v00);
            Y[(long)(row0 + r)      * HIDDEN + n0 + 16 + r16] = FAST_EXP2(v01);
            Y[(long)(row0 + 16 + r) * HIDDEN + n0 + r16]      = FAST_EXP2(v10);
            Y[(long)(row0 + 16 + r) * HIDDEN + n0 + 16 + r16] = FAST_EXP2(v11);
        }
    }
}

// ---------------- Scores v14: 4 t-rows share one pi pass -------------------
// R13 post-mortem: scores is BW-bound on the per-(b,t) pi re-read (411 MB).
// v14: block = (b, 4 t's, i-half) -> the same Ei row feeds 4 accumulators;
// pi traffic /4 = 103 MB. 512 blocks x 4 waves. Same math as v8.
__global__ __launch_bounds__(256) void scores_kernel(const float* __restrict__ pt,
        const float* __restrict__ pi, const float* __restrict__ wa,
        const float* __restrict__ ba, float* __restrict__ scores)
{
    const int blk = blockIdx.x;          // 0..511
    const int b = blk >> 6;
    const int rem = blk & 63;
    const int t0 = (rem >> 1) * 4;
    const int half = rem & 1;
    const int tid = threadIdx.x;
    const int lane = tid & 63, wave = tid >> 6;

    float4 pA[4], pB[4];
    #pragma unroll
    for (int t = 0; t < 4; ++t) {
        const float* ptrow = pt + (long)(b * T + t0 + t) * HIDDEN + lane * 8;
        pA[t] = *(const float4*)ptrow;
        pB[t] = *(const float4*)(ptrow + 4);
    }
    float4 wA = *(const float4*)(wa + lane * 8);
    float4 wB = *(const float4*)(wa + lane * 8 + 4);

    float S = wA.x + wA.y + wA.z + wA.w + wB.x + wB.y + wB.z + wB.w;
    #pragma unroll
    for (int off = 32; off; off >>= 1) S += __shfl_down(S, off);
    const float base = S + ba[0];        // consumed on lane 0 only

    wA.x *= -2.f; wA.y *= -2.f; wA.z *= -2.f; wA.w *= -2.f;
    wB.x *= -2.f; wB.y *= -2.f; wB.z *= -2.f; wB.w *= -2.f;

    const float* pib = pi + (long)b * I_TOK * HIDDEN + lane * 8;
    const int i0 = half * 98 + wave;
    const int iend = half * 98 + 98;

    float4 ca = *(const float4*)(pib + (long)i0 * HIDDEN);
    float4 cb = *(const float4*)(pib + (long)i0 * HIDDEN + 4);

    for (int i = i0; i < iend; i += 4) {
        const int inx = (i + 4 < iend) ? (i + 4) : i;
        const float4 na = *(const float4*)(pib + (long)inx * HIDDEN);
        const float4 nb = *(const float4*)(pib + (long)inx * HIDDEN + 4);

        float acc[4] = {0.f, 0.f, 0.f, 0.f};
        #pragma unroll
        for (int t = 0; t < 4; ++t) {
            acc[t] = fmaf(wA.x, FAST_RCP(fmaf(pA[t].x, ca.x, 1.f)), acc[t]);
            acc[t] = fmaf(wA.y, FAST_RCP(fmaf(pA[t].y, ca.y, 1.f)), acc[t]);
            acc[t] = fmaf(wA.z, FAST_RCP(fmaf(pA[t].z, ca.z, 1.f)), acc[t]);
            acc[t] = fmaf(wA.w, FAST_RCP(fmaf(pA[t].w, ca.w, 1.f)), acc[t]);
            acc[t] = fmaf(wB.x, FAST_RCP(fmaf(pB[t].x, cb.x, 1.f)), acc[t]);
            acc[t] = fmaf(wB.y, FAST_RCP(fmaf(pB[t].y, cb.y, 1.f)), acc[t]);
            acc[t] = fmaf(wB.z, FAST_RCP(fmaf(pB[t].z, cb.z, 1.f)), acc[t]);
            acc[t] = fmaf(wB.w, FAST_RCP(fmaf(pB[t].w, cb.w, 1.f)), acc[t]);
        }
        #pragma unroll
        for (int t = 0; t < 4; ++t) {
            #pragma unroll
            for (int off = 32; off; off >>= 1) acc[t] += __shfl_down(acc[t], off);
        }
        if (lane == 0) {
            #pragma unroll
            for (int t = 0; t < 4; ++t)
                scores[(long)(b * T + t0 + t) * I_TOK + i] = base + acc[t];
        }
        ca = na; cb = nb;
    }
}

// ---------------- Fused attended outputs v14 -------------------------------
// R13 post-mortem: att is BW-bound on the slab re-read (359 MB), occupancy-
// independent. v14 amortizes: text 8 t-rows/block (csplit 4, 512 blks,
// 103 MB); image 14 i-rows/block (csplit 3, 336 blks, 44 MB).
#define ATT_TEXT_BLOCKS (B * (T / 8) * 4)       // 512
#define ATT_IMG_BLOCKS  (3 * B * (I_TOK / 14))  // 336
#define ATT_GRID (ATT_TEXT_BLOCKS + ATT_IMG_BLOCKS)

__global__ __launch_bounds__(256) void att_kernel(const float* __restrict__ scores,
        const float* __restrict__ image, const float* __restrict__ text,
        float* __restrict__ out_text, float* __restrict__ out_img)
{
    __shared__ float sm[2048];                  // 8.2 KB (max of both paths)
    const int tid = threadIdx.x, lane = tid & 63, wave = tid >> 6;

    if (blockIdx.x < ATT_TEXT_BLOCKS) {
        const int bid = blockIdx.x;
        const int csplit = bid & 3;             // 4 x 256-col slices
        const int grp = bid >> 2;               // 0..127
        const int b = grp >> 4;
        const int t0 = (grp & 15) * 8;

        // softmax of 8 score rows; wave w does rows w and w+4 -> sm[i*8+r]
        #pragma unroll
        for (int rr = 0; rr < 2; ++rr) {
            const int r = wave + rr * 4;
            const float* srow = scores + ((long)(b * T + t0 + r)) * I_TOK;
            const float s0 = srow[lane];
            const float s1 = srow[lane + 64];
            const float s2 = srow[lane + 128];
            const float s3 = (lane < 4) ? srow[lane + 192] : -INFINITY;
            float m = fmaxf(fmaxf(s0, s1), fmaxf(s2, s3));
            #pragma unroll
            for (int off = 32; off; off >>= 1) m = fmaxf(m, __shfl_xor(m, off));
            const float e0 = __expf(s0 - m);
            const float e1 = __expf(s1 - m);
            const float e2 = __expf(s2 - m);
            const float e3 = (lane < 4) ? __expf(s3 - m) : 0.f;
            float sum = e0 + e1 + e2 + e3;
            #pragma unroll
            for (int off = 32; off; off >>= 1) sum += __shfl_xor(sum, off);
            const float inv = __fdividef(1.0f, sum);
            sm[lane * 8 + r] = e0 * inv;
            sm[(lane + 64) * 8 + r] = e1 * inv;
            sm[(lane + 128) * 8 + r] = e2 * inv;
            if (lane < 4) sm[(lane + 192) * 8 + r] = e3 * inv;
        }
        __syncthreads();

        const float* img = image + (long)b * I_TOK * IMAGE_DIM + csplit * 256 + tid;
        float acc[8] = {0.f,0.f,0.f,0.f,0.f,0.f,0.f,0.f};

        for (int g = 0; g < 49; ++g) {          // 196 = 49*4, batch-4 loads
            const int i = g * 4;
            const float v0 = img[(long)(i + 0) * IMAGE_DIM];
            const float v1 = img[(long)(i + 1) * IMAGE_DIM];
            const float v2 = img[(long)(i + 2) * IMAGE_DIM];
            const float v3 = img[(long)(i + 3) * IMAGE_DIM];
            #pragma unroll
            for (int k = 0; k < 4; ++k) {
                const float vk = (k == 0) ? v0 : (k == 1) ? v1 : (k == 2) ? v2 : v3;
                const float4 pa = *(const float4*)&sm[(i + k) * 8];
                const float4 pb = *(const float4*)&sm[(i + k) * 8 + 4];
                acc[0] = fmaf(pa.x, vk, acc[0]); acc[1] = fmaf(pa.y, vk, acc[1]);
                acc[2] = fmaf(pa.z, vk, acc[2]); acc[3] = fmaf(pa.w, vk, acc[3]);
                acc[4] = fmaf(pb.x, vk, acc[4]); acc[5] = fmaf(pb.y, vk, acc[5]);
                acc[6] = fmaf(pb.z, vk, acc[6]); acc[7] = fmaf(pb.w, vk, acc[7]);
            }
        }
        float* o = out_text + ((long)(b * T + t0)) * IMAGE_DIM + csplit * 256 + tid;
        #pragma unroll
        for (int r = 0; r < 8; ++r)
            o[(long)r * IMAGE_DIM] = acc[r];
    } else {
        const int bid = blockIdx.x - ATT_TEXT_BLOCKS;
        const int csplit = bid / 112;           // 0..2 (112 = 8*14)
        const int rem = bid % 112;
        const int b = rem / 14;
        const int i0 = (rem % 14) * 14;

        // softmax over t of 14 columns -> sm[t*16 + c]
        for (int c = wave; c < 14; c += 4) {
            const float* sc = scores + (long)b * T * I_TOK + (i0 + c);
            const float s0 = sc[(long)lane * I_TOK];
            const float s1 = sc[(long)(lane + 64) * I_TOK];
            float m = fmaxf(s0, s1);
            #pragma unroll
            for (int off = 32; off; off >>= 1) m = fmaxf(m, __shfl_xor(m, off));
            const float e0 = __expf(s0 - m);
            const float e1 = __expf(s1 - m);
            float sum = e0 + e1;
            #pragma unroll
            for (int off = 32; off; off >>= 1) sum += __shfl_xor(sum, off);
            const float inv = __fdividef(1.0f, sum);
            sm[lane * 16 + c] = e0 * inv;
            sm[(lane + 64) * 16 + c] = e1 * inv;
        }
        __syncthreads();

        const float* txt = text + (long)b * T * TEXT_DIM + csplit * 256 + tid;
        float acc[14];
        #pragma unroll
        for (int r = 0; r < 14; ++r) acc[r] = 0.f;

        for (int g = 0; g < 32; ++g) {          // 128 = 32*4, batch-4 loads
            const int t = g * 4;
            const float v0 = txt[(long)(t + 0) * TEXT_DIM];
            const float v1 = txt[(long)(t + 1) * TEXT_DIM];
            const float v2 = txt[(long)(t + 2) * TEXT_DIM];
            const float v3 = txt[(long)(t + 3) * TEXT_DIM];
            #pragma unroll
            for (int k = 0; k < 4; ++k) {
                const float vk = (k == 0) ? v0 : (k == 1) ? v1 : (k == 2) ? v2 : v3;
                const float4 q0 = *(const float4*)&sm[(t + k) * 16];
                const float4 q1 = *(const float4*)&sm[(t + k) * 16 + 4];
                const float4 q2 = *(const float4*)&sm[(t + k) * 16 + 8];
                const float2 q3 = *(const float2*)&sm[(t + k) * 16 + 12];
                acc[0]  = fmaf(q0.x, vk, acc[0]);  acc[1]  = fmaf(q0.y, vk, acc[1]);
                acc[2]  = fmaf(q0.z, vk, acc[2]);  acc[3]  = fmaf(q0.w, vk, acc[3]);
                acc[4]  = fmaf(q1.x, vk, acc[4]);  acc[5]  = fmaf(q1.y, vk, acc[5]);
                acc[6]  = fmaf(q1.z, vk, acc[6]);  acc[7]  = fmaf(q1.w, vk, acc[7]);
                acc[8]  = fmaf(q2.x, vk, acc[8]);  acc[9]  = fmaf(q2.y, vk, acc[9]);
                acc[10] = fmaf(q2.z, vk, acc[10]); acc[11] = fmaf(q2.w, vk, acc[11]);
                acc[12] = fmaf(q3.x, vk, acc[12]); acc[13] = fmaf(q3.y, vk, acc[13]);
            }
        }
        float* o = out_img + ((long)b * I_TOK + i0) * TEXT_DIM + csplit * 256 + tid;
        #pragma unroll
        for (int r = 0; r < 14; ++r)
            o[(long)r * TEXT_DIM] = acc[r];
    }
}

extern "C" void kernel_launch(void* const* d_in, const int* in_sizes, int n_in,
                              void* d_out, int out_size, void* d_ws, size_t ws_size,
                              hipStream_t stream) {
    const float* text  = (const float*)d_in[0];
    const float* image = (const float*)d_in[1];
    const float* Wt    = (const float*)d_in[2];
    const float* bt    = (const float*)d_in[3];
    const float* Wi    = (const float*)d_in[4];
    const float* bi    = (const float*)d_in[5];
    const float* wa    = (const float*)d_in[6];
    const float* ba    = (const float*)d_in[7];

    float* pt = (float*)d_ws;                       // Et = exp2-transformed
    float* pi = pt + (long)B * T * HIDDEN;          // Ei
    float* sc = pi + (long)B * I_TOK * HIDDEN;
    unsigned short* Xh  = (unsigned short*)(sc + (long)B * T * I_TOK);
    unsigned short* Xl  = Xh + X_ELEMS;
    unsigned short* WTh = Xl + X_ELEMS;
    unsigned short* WTl = WTh + W_ELEMS;

    float* out_text = (float*)d_out;                        // B*T*IMAGE_DIM
    float* out_img  = out_text + (long)B * T * IMAGE_DIM;   // B*I*TEXT_DIM

    prep_kernel<<<PREP_GRID, 256, 0, stream>>>(text, image, Wt, Wi, Xh, Xl, WTh, WTl);
    mfma_proj_kernel<<<GEMM_GRID, 256, 0, stream>>>(Xh, Xl, WTh, WTl, bt, bi, pt, pi);
    scores_kernel<<<B * (T / 4) * 2, 256, 0, stream>>>(pt, pi, wa, ba, sc);
    att_kernel<<<ATT_GRID, 256, 0, stream>>>(sc, image, text, out_text, out_img);
}